// Round 3
// baseline (2766.669 us; speedup 1.0000x reference)
//
#include <hip/hip_runtime.h>

// Residual VQ: N=65536, D=256, K=1024, 4 codebooks.
// Inputs: bf16 (runtime-detected, f32 fallback): z [N][D], cb [4][K][D].
// Output: FLOAT32 concat: quant_sum [N][D] | inds [N][4] | loss [1].
//
// Round 12: spill-elimination for the 8x8 tile. R10/R11 showed the VGPR
// budget is pinned at 128 regardless of launch-bounds/waves-per-eu hints;
// the allocator spilled the coldest 32-reg block, q[32] (dead across the
// whole dc loop): 256 B/thread/cb round-trips ~= the measured ~500 MB
// symmetric scratch excess.
//  - NEW: q[32] removed. quant_sum accumulates IN GLOBAL out[]: cb==0
//    writes (0.0f + s) (bit-identical to q=0; q+=s, incl. -0.0), cb>0 does
//    read+add+write. Each block's 32 KB quant slice stays L2-resident
//    between codebooks (64 blocks/XCD x 32 KB = 2 MB < 4 MB L2).
//  - Peak live set now ~120 VGPRs (acc 64 + bval/bidx 16 + av 32 transient
//    + misc) => fits the 128 budget, no spills expected.
//  - numpy-f32 bitwise scoring chain preserved EXACTLY: sequential fmaf dot
//    (d=0..255), AVX512-W16 pairwise r2/w2, dist = fl(fl(r2-2dot)+w2),
//    first-index ties (j-outer/i-inner, k ascending), elementwise ST dance.
//  - Predicted: WRITE 495->~100-260 MB, FETCH 396->~40-240 MB,
//    dur ~1.5-2.0 ms, VALUBusy 72-85%.
// Rules: no __shfl, single instantiation, LDS-tree reductions, canary.

#define N_TOK 65536
#define DIM   256
#define KCB   1024
#define NCBK  4

#define TM  32          // rows per block
#define TK  512         // codes per k-tile (2 tiles per codebook)
#define DC  16          // d-chunk per W stage
#define RST 260         // f32 LDS stride, residual rows (16B-aligned)
#define WST 18          // f32 LDS stride, W rows (==2 mod 32: free 2-way, 8B-aligned)

#define QS_F   ((size_t)N_TOK * DIM)             // 16777216 f32 elements
#define IDX_F  QS_F
#define IDXE_F (IDX_F + (size_t)N_TOK * NCBK)    // 17039360
#define LOSS_F IDXE_F                            // 17039360

// d_ws: float w2f[4096] @0 | double partials[2048] @16384 | int flags[2] @32768
#define WS_PART_OFF 16384
#define WS_FLAG_OFF 32768

typedef unsigned short u16;
typedef unsigned int   u32;

__device__ __forceinline__ float bf2f(u32 h) { return __uint_as_float(h << 16); }

__device__ __forceinline__ float getv(const void* base, int f32in, size_t elt) {
    if (f32in) return ((const float*)base)[elt];
    return bf2f(((const u16*)base)[elt]);
}

// All call sites pass elt % 8 == 0 => 32B (f32) / 16B (bf16) aligned.
__device__ __forceinline__ void load8(const void* base, int f32in, size_t elt,
                                      float* f) {
    if (f32in) {
        const float4* p = (const float4*)((const float*)base + elt);
        float4 a = p[0], b = p[1];
        f[0] = a.x; f[1] = a.y; f[2] = a.z; f[3] = a.w;
        f[4] = b.x; f[5] = b.y; f[6] = b.z; f[7] = b.w;
    } else {
        uint4 q = *(const uint4*)((const u16*)base + elt);
        f[0] = bf2f(q.x & 0xffffu); f[1] = bf2f(q.x >> 16);
        f[2] = bf2f(q.y & 0xffffu); f[3] = bf2f(q.y >> 16);
        f[4] = bf2f(q.z & 0xffffu); f[5] = bf2f(q.z >> 16);
        f[6] = bf2f(q.w & 0xffffu); f[7] = bf2f(q.w >> 16);
    }
}

// canary: stamp f32 index region + loss with 512.0f (decodable no-op signal)
__global__ void canary_kernel(float* out) {
    int gid = blockIdx.x * 256 + threadIdx.x;
    size_t pos = IDX_F + (size_t)gid;
    if (pos < IDXE_F) out[pos] = 512.0f;
    if (gid == 0) out[LOSS_F] = 512.0f;
}

// dtype detect (bf16 vs f32), proven in rounds 7/8
__global__ void detect_kernel(const u16* z16, const u16* cb16, int* flags) {
    __shared__ int s0[256], s1[256];
    int tid = threadIdx.x;
    u32 a = z16[tid],  ea = (a >> 7) & 0xffu;
    u32 b = cb16[tid], eb = (b >> 7) & 0xffu;
    s0[tid] = ((ea >= 90u && ea <= 140u) || ((a & 0x7fffu) == 0u)) ? 1 : 0;
    s1[tid] = ((eb >= 90u && eb <= 140u) || ((b & 0x7fffu) == 0u)) ? 1 : 0;
    __syncthreads();
    for (int st = 128; st > 0; st >>= 1) {
        if (tid < st) { s0[tid] += s0[tid + st]; s1[tid] += s1[tid + st]; }
        __syncthreads();
    }
    if (tid == 0) { flags[0] = (s0[0] < 218) ? 1 : 0;   // 1 => f32
                    flags[1] = (s1[0] < 218) ? 1 : 0; }
}

// numpy pairwise sum-of-squares, one 128 block, AVX512 W=16 order
__device__ __forceinline__ float np128_sq_g(const void* base, int f32in, size_t off) {
    float S[16];
    #pragma unroll
    for (int l = 0; l < 16; ++l) {
        float A[8];
        #pragma unroll
        for (int j = 0; j < 8; ++j) {
            float x = getv(base, f32in, off + 16 * j + l);
            A[j] = x * x;
        }
        S[l] = ((A[0] + A[1]) + (A[2] + A[3])) + ((A[4] + A[5]) + (A[6] + A[7]));
    }
    float B1[8], B2[4];
    #pragma unroll
    for (int l = 0; l < 8; ++l) B1[l] = S[l] + S[l + 8];
    #pragma unroll
    for (int l = 0; l < 4; ++l) B2[l] = B1[l] + B1[l + 4];
    return (B2[0] + B2[2]) + (B2[1] + B2[3]);
}

__device__ __forceinline__ float np128_sq_lds(const float* a) {
    float S[16];
    #pragma unroll
    for (int l = 0; l < 16; ++l) {
        float A[8];
        #pragma unroll
        for (int j = 0; j < 8; ++j) { float x = a[16 * j + l]; A[j] = x * x; }
        S[l] = ((A[0] + A[1]) + (A[2] + A[3])) + ((A[4] + A[5]) + (A[6] + A[7]));
    }
    float B1[8], B2[4];
    #pragma unroll
    for (int l = 0; l < 8; ++l) B1[l] = S[l] + S[l + 8];
    #pragma unroll
    for (int l = 0; l < 4; ++l) B2[l] = B1[l] + B1[l + 4];
    return (B2[0] + B2[2]) + (B2[1] + B2[3]);
}

__global__ void w2_kernel(const void* cbs, float* w2f, const int* flags) {
    int kf = blockIdx.x * 256 + threadIdx.x;      // 0..4095
    const int fc = flags[1];
    size_t base = (size_t)kf * DIM;
    w2f[kf] = np128_sq_g(cbs, fc, base) + np128_sq_g(cbs, fc, base + 128);
}

__global__
__attribute__((amdgpu_flat_work_group_size(256, 256), amdgpu_waves_per_eu(2, 2)))
void rq_kernel(const void* z, const void* cbs, const float* w2f,
               float* out, double* partials, const int* flags) {
    __shared__ float  Rld[TM * RST];        // 33280 B
    __shared__ float  Wld[TK * WST];        // 36864 B (cand arrays overlay here)
    __shared__ float  r2s[TM];              //   128 B
    __shared__ int    bestk[TM];            //   128 B
    __shared__ double dred[256];            //  2048 B  => 72448 B (2 blk/CU)

    // candidate argmin overlay: only live between the post-kt barrier and
    // the pre-dance barrier, when Wld has no staged W data.
    float* candv = Wld;                     // [32][65]
    int*   candi = (int*)(Wld + TM * 65);   // [32][65]

    const int fz = flags[0], fc = flags[1];
    const int tid  = threadIdx.x;
    const int tx   = tid & 31;              // code lane
    const int ty   = tid >> 5;              // 0..7
    const int rowg = ty & 3;                // row group: rows rowg+4i, i=0..7
    const int cg   = ty >> 2;               // code half: codes tx+32j+256cg
    const int row0 = blockIdx.x * TM;

    // staging constants: flat = it*256+tid -> k = it*128 + (tid>>1), dp = (tid&1)*8
    const int stg_k0 = tid >> 1;
    const int stg_dp = (tid & 1) * 8;

    for (int it = 0; it < 4; ++it) {
        int flat = it * 256 + tid;
        int r = flat >> 5, c8 = flat & 31;
        float f[8];
        load8(z, fz, (size_t)(row0 + r) * DIM + c8 * 8, f);
        int base = r * RST + c8 * 8;
        #pragma unroll
        for (int e = 0; e < 8; ++e) Rld[base + e] = f[e];
    }
    double lsum = 0.0;

    for (int cb = 0; cb < NCBK; ++cb) {
        const size_t cbW = (size_t)cb * KCB * DIM;
        const float* w2c = w2f + cb * KCB;

        __syncthreads();                     // Rld settled
        if (tid < TM) {                      // r2 = np pairwise sum(r*r)
            const float* a = &Rld[tid * RST];
            r2s[tid] = np128_sq_lds(a) + np128_sq_lds(a + 128);
        }
        __syncthreads();

        float bval[8]; int bidx[8];
        #pragma unroll
        for (int i = 0; i < 8; ++i) { bval[i] = __uint_as_float(0x7f7fffffu); bidx[i] = 0; }

        for (int kt = 0; kt < KCB / TK; ++kt) {          // 2 tiles of 512 codes
            float acc[8][8];                 // sequential-d f32 chains
            #pragma unroll
            for (int i = 0; i < 8; ++i)
                #pragma unroll
                for (int j = 0; j < 8; ++j) acc[i][j] = 0.f;

            for (int dc = 0; dc < DIM / DC; ++dc) {      // 16 chunks of 16 d
                __syncthreads();             // prior Wld readers done
                #pragma unroll
                for (int it = 0; it < 4; ++it) {   // stage [512]x[16] W chunk
                    int k  = it * 128 + stg_k0;    // 0..511
                    float f[8];
                    load8(cbs, fc, cbW + (size_t)(kt * TK + k) * DIM + dc * DC + stg_dp, f);
                    int wb = k * WST + stg_dp;     // even => b64-aligned
                    *(float2*)&Wld[wb]     = make_float2(f[0], f[1]);
                    *(float2*)&Wld[wb + 2] = make_float2(f[2], f[3]);
                    *(float2*)&Wld[wb + 4] = make_float2(f[4], f[5]);
                    *(float2*)&Wld[wb + 6] = make_float2(f[6], f[7]);
                }
                __syncthreads();

                #pragma unroll
                for (int dd = 0; dd < DC / 4; ++dd) {
                    float av[8][4];
                    #pragma unroll
                    for (int i = 0; i < 8; ++i) {
                        const float4 va = *(const float4*)
                            &Rld[(rowg + 4 * i) * RST + dc * DC + dd * 4];
                        av[i][0] = va.x; av[i][1] = va.y;
                        av[i][2] = va.z; av[i][3] = va.w;
                    }
                    #pragma unroll
                    for (int j = 0; j < 8; ++j) {
                        const int c = tx + 32 * j + 256 * cg;
                        const float2* wp = (const float2*)&Wld[c * WST + dd * 4];
                        const float2 b01 = wp[0];
                        const float2 b23 = wp[1];
                        #pragma unroll
                        for (int i = 0; i < 8; ++i) {
                            float s = acc[i][j];
                            s = fmaf(av[i][0], b01.x, s);   // d ascending:
                            s = fmaf(av[i][1], b01.y, s);   // BLAS sgemm
                            s = fmaf(av[i][2], b23.x, s);   // sequential-k
                            s = fmaf(av[i][3], b23.y, s);   // FMA chain
                            acc[i][j] = s;
                        }
                    }
                }
            }
            // dist = fl(fl(r2 - 2*dot) + w2), f32; first-index ties.
            // r2 read from LDS here (broadcast) instead of carried registers.
            #pragma unroll
            for (int j = 0; j < 8; ++j) {
                const int k = kt * TK + tx + 32 * j + 256 * cg;
                const float w2k = w2c[k];
                #pragma unroll
                for (int i = 0; i < 8; ++i) {
                    float t2   = r2s[rowg + 4 * i] - 2.0f * acc[i][j];
                    float dist = t2 + w2k;
                    if (dist < bval[i] || (dist == bval[i] && k < bidx[i])) {
                        bval[i] = dist; bidx[i] = k;
                    }
                }
            }
        }
        // argmin across 64 candidate slots per row via LDS (no shuffles)
        __syncthreads();                     // all Wld reads done -> overlay safe
        #pragma unroll
        for (int i = 0; i < 8; ++i) {
            int r = rowg + 4 * i;
            candv[r * 65 + tx + 32 * cg] = bval[i];
            candi[r * 65 + tx + 32 * cg] = bidx[i];
        }
        __syncthreads();
        if (tid < TM) {
            float best = candv[tid * 65];
            int   bi   = candi[tid * 65];
            for (int t = 1; t < 64; ++t) {
                float v = candv[tid * 65 + t];
                int  ix = candi[tid * 65 + t];
                if (v < best || (v == best && ix < bi)) { best = v; bi = ix; }
            }
            bestk[tid] = bi;
            size_t pos = IDX_F + (size_t)(row0 + tid) * NCBK + cb;
            if (pos < IDXE_F) out[pos] = (float)bi;
        }
        __syncthreads();
        // straight-through dance, elementwise f32 (np bit order):
        // t = zq - r; s = r + t; r' = r - s; q += s; loss += t^2
        // q lives in GLOBAL out[]: cb==0 writes (0+s), else read+add+write.
        // Same f32 chain (((0+s1)+s2)+s3)+s4 as the old register q.
        #pragma unroll
        for (int it = 0; it < 4; ++it) {
            int flat = it * 256 + tid;
            int r = flat >> 5, c8 = flat & 31;
            int kb = bestk[r];
            float f[8];
            load8(cbs, fc, cbW + (size_t)kb * DIM + c8 * 8, f);
            int base = r * RST + c8 * 8;
            size_t pos = (size_t)(row0 + r) * DIM + c8 * 8;
            float qv[8];
            if (cb == 0) {
                #pragma unroll
                for (int e = 0; e < 8; ++e) qv[e] = 0.0f;
            } else {
                float4 o0 = *(const float4*)&out[pos];
                float4 o1 = *(const float4*)&out[pos + 4];
                qv[0] = o0.x; qv[1] = o0.y; qv[2] = o0.z; qv[3] = o0.w;
                qv[4] = o1.x; qv[5] = o1.y; qv[6] = o1.z; qv[7] = o1.w;
            }
            #pragma unroll
            for (int e = 0; e < 8; ++e) {
                float rv = Rld[base + e];
                float t  = f[e] - rv;
                float s  = rv + t;
                float rn = rv - s;
                Rld[base + e] = rn;
                qv[e] = qv[e] + s;
                lsum += (double)t * (double)t;
            }
            float4 w0 = make_float4(qv[0], qv[1], qv[2], qv[3]);
            float4 w1 = make_float4(qv[4], qv[5], qv[6], qv[7]);
            *(float4*)&out[pos]     = w0;
            *(float4*)&out[pos + 4] = w1;
        }
        __syncthreads();
    }

    // loss: per-block f64 LDS tree -> partials[block]
    dred[tid] = lsum;
    __syncthreads();
    for (int s = 128; s > 0; s >>= 1) {
        if (tid < s) dred[tid] += dred[tid + s];
        __syncthreads();
    }
    if (tid == 0) partials[blockIdx.x] = dred[0];
}

__global__ void loss_final(const double* partials, float* out) {
    __shared__ double sred[256];
    int tid = threadIdx.x;
    double s = 0.0;
    for (int q = 0; q < 8; ++q) s += partials[tid + 256 * q];
    sred[tid] = s;
    __syncthreads();
    for (int st = 128; st > 0; st >>= 1) {
        if (tid < st) sred[tid] += sred[tid + st];
        __syncthreads();
    }
    if (tid == 0)
        out[LOSS_F] = (float)(2.0 * sred[0] / 16777216.0);  // 2*S/(N*D)
}

extern "C" void kernel_launch(void* const* d_in, const int* in_sizes, int n_in,
                              void* d_out, int out_size, void* d_ws, size_t ws_size,
                              hipStream_t stream) {
    (void)n_in; (void)out_size; (void)ws_size;
    const void* z;
    const void* cbs;
    if (in_sizes[0] == 16777216) { z = d_in[0]; cbs = d_in[1]; }
    else                         { z = d_in[1]; cbs = d_in[0]; }

    float*  out      = (float*)d_out;
    float*  w2f      = (float*)d_ws;
    double* partials = (double*)((char*)d_ws + WS_PART_OFF);
    int*    flags    = (int*)((char*)d_ws + WS_FLAG_OFF);

    canary_kernel<<<1024, 256, 0, stream>>>(out);
    detect_kernel<<<1, 256, 0, stream>>>((const u16*)z, (const u16*)cbs, flags);
    w2_kernel<<<16, 256, 0, stream>>>(cbs, w2f, flags);
    rq_kernel<<<N_TOK / TM, 256, 0, stream>>>(z, cbs, w2f, out, partials, flags);
    loss_final<<<1, 256, 0, stream>>>(partials, out);
}

// Round 4
// 2660.372 us; speedup vs baseline: 1.0400x; 1.0400x over previous
//
#include <hip/hip_runtime.h>

// Residual VQ: N=65536, D=256, K=1024, 4 codebooks.
// Inputs: bf16 (runtime-detected, f32 fallback): z [N][D], cb [4][K][D].
// Output: FLOAT32 concat: quant_sum [N][D] | inds [N][4] | loss [1].
//
// Round 13: LDS-instruction-count pass. R10-R12 (8x8 tile) dead end: VGPR
// allocator pins 128 regardless of hints; spill/RMW traffic ate the gains.
// Revert to R9's proven 4x8 structure (2632us, no spill) and cut the LDS
// pipe load, which a per-instruction model shows is 1.25x oversubscribed
// (model reproduces R9's 2632us within 2%).
//  - NEW Wld layout: linear 512 rows x 16 floats (code k's 32-d chunk ->
//    half-rows k and k+256), XOR-swizzled at 16B granules:
//    fi = (row*16 + g*4) ^ (((row>>1)&7)<<2). Key uses row>>1 only =>
//    bijective within each 128B row-pair; 16B alignment preserved.
//  - B-reads: ONE ds_read_b128 per code per dd (was 2x b64), 2-way bank
//    (free): lanes map to 16 bank-groups x 2. A-reads: explicit float4.
//  - Staging writes: 2x b128 per load8 (was 8x b32).
//  - numpy-f32 bitwise scoring chain preserved EXACTLY: sequential fmaf dot
//    (d=0..255), AVX512-W16 pairwise r2/w2, dist = fl(fl(r2-2dot)+w2),
//    first-index ties (j-outer/i-inner, k ascending), elementwise ST dance,
//    q[32] in registers (R9 style).
//  - Predicted: dur ~2250-2450us, conflicts <=1.2e8, VALUBusy 75-82%,
//    FETCH/WRITE ~140/164 MB.
// Rules: no __shfl, single instantiation, LDS-tree reductions, canary.

#define N_TOK 65536
#define DIM   256
#define KCB   1024
#define NCBK  4

#define TM  32          // rows per block
#define TK  256         // codes per k-tile (4 tiles per codebook)
#define DC  32          // d-chunk per W stage
#define RST 260         // f32 LDS stride, residual rows (16B-aligned)

#define QS_F   ((size_t)N_TOK * DIM)             // 16777216 f32 elements
#define IDX_F  QS_F
#define IDXE_F (IDX_F + (size_t)N_TOK * NCBK)    // 17039360
#define LOSS_F IDXE_F                            // 17039360

// d_ws: float w2f[4096] @0 | double partials[2048] @16384 | int flags[2] @32768
#define WS_PART_OFF 16384
#define WS_FLAG_OFF 32768

typedef unsigned short u16;
typedef unsigned int   u32;

__device__ __forceinline__ float bf2f(u32 h) { return __uint_as_float(h << 16); }

__device__ __forceinline__ float getv(const void* base, int f32in, size_t elt) {
    if (f32in) return ((const float*)base)[elt];
    return bf2f(((const u16*)base)[elt]);
}

// All call sites pass elt % 8 == 0 => 32B (f32) / 16B (bf16) aligned.
__device__ __forceinline__ void load8(const void* base, int f32in, size_t elt,
                                      float* f) {
    if (f32in) {
        const float4* p = (const float4*)((const float*)base + elt);
        float4 a = p[0], b = p[1];
        f[0] = a.x; f[1] = a.y; f[2] = a.z; f[3] = a.w;
        f[4] = b.x; f[5] = b.y; f[6] = b.z; f[7] = b.w;
    } else {
        uint4 q = *(const uint4*)((const u16*)base + elt);
        f[0] = bf2f(q.x & 0xffffu); f[1] = bf2f(q.x >> 16);
        f[2] = bf2f(q.y & 0xffffu); f[3] = bf2f(q.y >> 16);
        f[4] = bf2f(q.z & 0xffffu); f[5] = bf2f(q.z >> 16);
        f[6] = bf2f(q.w & 0xffffu); f[7] = bf2f(q.w >> 16);
    }
}

// canary: stamp f32 index region + loss with 512.0f (decodable no-op signal)
__global__ void canary_kernel(float* out) {
    int gid = blockIdx.x * 256 + threadIdx.x;
    size_t pos = IDX_F + (size_t)gid;
    if (pos < IDXE_F) out[pos] = 512.0f;
    if (gid == 0) out[LOSS_F] = 512.0f;
}

// dtype detect (bf16 vs f32), proven in rounds 7/8
__global__ void detect_kernel(const u16* z16, const u16* cb16, int* flags) {
    __shared__ int s0[256], s1[256];
    int tid = threadIdx.x;
    u32 a = z16[tid],  ea = (a >> 7) & 0xffu;
    u32 b = cb16[tid], eb = (b >> 7) & 0xffu;
    s0[tid] = ((ea >= 90u && ea <= 140u) || ((a & 0x7fffu) == 0u)) ? 1 : 0;
    s1[tid] = ((eb >= 90u && eb <= 140u) || ((b & 0x7fffu) == 0u)) ? 1 : 0;
    __syncthreads();
    for (int st = 128; st > 0; st >>= 1) {
        if (tid < st) { s0[tid] += s0[tid + st]; s1[tid] += s1[tid + st]; }
        __syncthreads();
    }
    if (tid == 0) { flags[0] = (s0[0] < 218) ? 1 : 0;   // 1 => f32
                    flags[1] = (s1[0] < 218) ? 1 : 0; }
}

// numpy pairwise sum-of-squares, one 128 block, AVX512 W=16 order
__device__ __forceinline__ float np128_sq_g(const void* base, int f32in, size_t off) {
    float S[16];
    #pragma unroll
    for (int l = 0; l < 16; ++l) {
        float A[8];
        #pragma unroll
        for (int j = 0; j < 8; ++j) {
            float x = getv(base, f32in, off + 16 * j + l);
            A[j] = x * x;
        }
        S[l] = ((A[0] + A[1]) + (A[2] + A[3])) + ((A[4] + A[5]) + (A[6] + A[7]));
    }
    float B1[8], B2[4];
    #pragma unroll
    for (int l = 0; l < 8; ++l) B1[l] = S[l] + S[l + 8];
    #pragma unroll
    for (int l = 0; l < 4; ++l) B2[l] = B1[l] + B1[l + 4];
    return (B2[0] + B2[2]) + (B2[1] + B2[3]);
}

__device__ __forceinline__ float np128_sq_lds(const float* a) {
    float S[16];
    #pragma unroll
    for (int l = 0; l < 16; ++l) {
        float A[8];
        #pragma unroll
        for (int j = 0; j < 8; ++j) { float x = a[16 * j + l]; A[j] = x * x; }
        S[l] = ((A[0] + A[1]) + (A[2] + A[3])) + ((A[4] + A[5]) + (A[6] + A[7]));
    }
    float B1[8], B2[4];
    #pragma unroll
    for (int l = 0; l < 8; ++l) B1[l] = S[l] + S[l + 8];
    #pragma unroll
    for (int l = 0; l < 4; ++l) B2[l] = B1[l] + B1[l + 4];
    return (B2[0] + B2[2]) + (B2[1] + B2[3]);
}

__global__ void w2_kernel(const void* cbs, float* w2f, const int* flags) {
    int kf = blockIdx.x * 256 + threadIdx.x;      // 0..4095
    const int fc = flags[1];
    size_t base = (size_t)kf * DIM;
    w2f[kf] = np128_sq_g(cbs, fc, base) + np128_sq_g(cbs, fc, base + 128);
}

__global__ __launch_bounds__(256, 2)
void rq_kernel(const void* z, const void* cbs, const float* w2f,
               float* out, double* partials, const int* flags) {
    __shared__ float  Rld[TM * RST];        // 33280 B
    __shared__ float  Wld[512 * 16];        // 32768 B, swizzled (see header)
    __shared__ float  candv[TM * 33];       //  4224 B
    __shared__ int    candi[TM * 33];       //  4224 B
    __shared__ float  r2s[TM];              //   128 B
    __shared__ int    bestk[TM];            //   128 B
    __shared__ double dred[256];            //  2048 B  => 76800 B (2 blk/CU)

    const int fz = flags[0], fc = flags[1];
    const int tid  = threadIdx.x;
    const int tx   = tid & 31;              // code lane
    const int ty   = tid >> 5;              // row group 0..7 (rows ty+8i)
    const int row0 = blockIdx.x * TM;

    // swizzle key for B-reads: row = tx+32j+256h => (row>>1)&7 == (tx>>1)&7
    // (32j and 256h contribute multiples of 16 to row>>1 => drop mod 8).
    const int K2 = ((tx >> 1) & 7) << 2;    // float-index XOR key (bits 2-4)

    float q[32];
    #pragma unroll
    for (int e = 0; e < 32; ++e) q[e] = 0.f;

    for (int it = 0; it < 4; ++it) {
        int flat = it * 256 + tid;
        int r = flat >> 5, c8 = flat & 31;
        float f[8];
        load8(z, fz, (size_t)(row0 + r) * DIM + c8 * 8, f);
        int base = r * RST + c8 * 8;
        #pragma unroll
        for (int e = 0; e < 8; ++e) Rld[base + e] = f[e];
    }
    double lsum = 0.0;

    for (int cb = 0; cb < NCBK; ++cb) {
        const size_t cbW = (size_t)cb * KCB * DIM;
        const float* w2c = w2f + cb * KCB;

        __syncthreads();                     // Rld settled
        if (tid < TM) {                      // r2 = np pairwise sum(r*r)
            const float* a = &Rld[tid * RST];
            r2s[tid] = np128_sq_lds(a) + np128_sq_lds(a + 128);
        }
        __syncthreads();

        float r2v[4];
        #pragma unroll
        for (int i = 0; i < 4; ++i) r2v[i] = r2s[ty + 8 * i];

        float bval[4]; int bidx[4];
        #pragma unroll
        for (int i = 0; i < 4; ++i) { bval[i] = __uint_as_float(0x7f7fffffu); bidx[i] = 0; }

        for (int kt = 0; kt < KCB / TK; ++kt) {          // 4 tiles of 256 codes
            float acc[4][8];                 // sequential-d f32 chains
            #pragma unroll
            for (int i = 0; i < 4; ++i)
                #pragma unroll
                for (int j = 0; j < 8; ++j) acc[i][j] = 0.f;

            for (int dc = 0; dc < DIM / DC; ++dc) {      // 8 chunks of 32 d
                __syncthreads();             // prior Wld readers done
                #pragma unroll
                for (int it = 0; it < 4; ++it) {   // stage [256]x[32] W chunk
                    int k  = it * 64 + (tid >> 2);
                    int dp = (tid & 3) * 8;
                    float f[8];
                    load8(cbs, fc, cbW + (size_t)(kt * TK + k) * DIM + dc * DC + dp, f);
                    // swizzled store: row = k + 256*(dp>=16), granules g,g+1
                    int row = k + ((dp >> 4) << 8);
                    int kw2 = ((k >> 1) & 7) << 2;
                    int g0  = (dp & 15) >> 2;            // 0 or 2
                    int fi0 = ((row << 4) + (g0 << 2)) ^ kw2;
                    int fi1 = ((row << 4) + ((g0 + 1) << 2)) ^ kw2;
                    *(float4*)&Wld[fi0] = make_float4(f[0], f[1], f[2], f[3]);
                    *(float4*)&Wld[fi1] = make_float4(f[4], f[5], f[6], f[7]);
                }
                __syncthreads();

                #pragma unroll
                for (int dd = 0; dd < DC / 4; ++dd) {    // 8 sub-steps of 4 d
                    float4 av[4];
                    #pragma unroll
                    for (int i = 0; i < 4; ++i)
                        av[i] = *(const float4*)
                            &Rld[(ty + 8 * i) * RST + dc * DC + dd * 4];
                    // tb: half-plane offset (4096*h) + granule offset (4*dd4)
                    const int tb = ((dd >> 2) << 12) + ((dd & 3) << 2);
                    #pragma unroll
                    for (int j = 0; j < 8; ++j) {
                        const int fi = (((tx + 32 * j) << 4) + tb) ^ K2;
                        const float4 bv = *(const float4*)&Wld[fi];
                        #pragma unroll
                        for (int i = 0; i < 4; ++i) {
                            float s = acc[i][j];
                            s = fmaf(av[i].x, bv.x, s);   // d ascending:
                            s = fmaf(av[i].y, bv.y, s);   // BLAS sgemm
                            s = fmaf(av[i].z, bv.z, s);   // sequential-k
                            s = fmaf(av[i].w, bv.w, s);   // FMA chain
                            acc[i][j] = s;
                        }
                    }
                }
            }
            // dist = fl(fl(r2 - 2*dot) + w2), f32; first-index ties
            #pragma unroll
            for (int j = 0; j < 8; ++j) {
                int k = kt * TK + tx + 32 * j;
                float w2k = w2c[k];
                #pragma unroll
                for (int i = 0; i < 4; ++i) {
                    float t2   = r2v[i] - 2.0f * acc[i][j];
                    float dist = t2 + w2k;
                    if (dist < bval[i] || (dist == bval[i] && k < bidx[i])) {
                        bval[i] = dist; bidx[i] = k;
                    }
                }
            }
        }
        // argmin across 32 lanes via LDS (no shuffles)
        __syncthreads();
        #pragma unroll
        for (int i = 0; i < 4; ++i) {
            int r = ty + 8 * i;
            candv[r * 33 + tx] = bval[i];
            candi[r * 33 + tx] = bidx[i];
        }
        __syncthreads();
        if (tid < TM) {
            float best = candv[tid * 33];
            int   bi   = candi[tid * 33];
            for (int t = 1; t < 32; ++t) {
                float v = candv[tid * 33 + t];
                int  ix = candi[tid * 33 + t];
                if (v < best || (v == best && ix < bi)) { best = v; bi = ix; }
            }
            bestk[tid] = bi;
            size_t pos = IDX_F + (size_t)(row0 + tid) * NCBK + cb;
            if (pos < IDXE_F) out[pos] = (float)bi;
        }
        __syncthreads();
        // straight-through dance, elementwise f32 (np bit order):
        // t = zq - r; s = r + t; r' = r - s; q += s; loss += t^2
        #pragma unroll
        for (int it = 0; it < 4; ++it) {
            int flat = it * 256 + tid;
            int r = flat >> 5, c8 = flat & 31;
            int kb = bestk[r];
            float f[8];
            load8(cbs, fc, cbW + (size_t)kb * DIM + c8 * 8, f);
            int base = r * RST + c8 * 8;
            #pragma unroll
            for (int e = 0; e < 8; ++e) {
                float rv = Rld[base + e];
                float t  = f[e] - rv;
                float s  = rv + t;
                float rn = rv - s;
                Rld[base + e] = rn;
                q[it * 8 + e] = q[it * 8 + e] + s;
                lsum += (double)t * (double)t;
            }
        }
        __syncthreads();
    }

    // quant_sum writes from registers (f32)
    #pragma unroll
    for (int it = 0; it < 4; ++it) {
        int flat = it * 256 + tid;
        int r = flat >> 5, c8 = flat & 31;
        size_t pos = (size_t)(row0 + r) * DIM + c8 * 8;
        if (pos + 8 <= QS_F) {
            #pragma unroll
            for (int e = 0; e < 8; ++e) out[pos + e] = q[it * 8 + e];
        }
    }

    // loss: per-block f64 LDS tree -> partials[block]
    dred[tid] = lsum;
    __syncthreads();
    for (int s = 128; s > 0; s >>= 1) {
        if (tid < s) dred[tid] += dred[tid + s];
        __syncthreads();
    }
    if (tid == 0) partials[blockIdx.x] = dred[0];
}

__global__ void loss_final(const double* partials, float* out) {
    __shared__ double sred[256];
    int tid = threadIdx.x;
    double s = 0.0;
    for (int q = 0; q < 8; ++q) s += partials[tid + 256 * q];
    sred[tid] = s;
    __syncthreads();
    for (int st = 128; st > 0; st >>= 1) {
        if (tid < st) sred[tid] += sred[tid + st];
        __syncthreads();
    }
    if (tid == 0)
        out[LOSS_F] = (float)(2.0 * sred[0] / 16777216.0);  // 2*S/(N*D)
}

extern "C" void kernel_launch(void* const* d_in, const int* in_sizes, int n_in,
                              void* d_out, int out_size, void* d_ws, size_t ws_size,
                              hipStream_t stream) {
    (void)n_in; (void)out_size; (void)ws_size;
    const void* z;
    const void* cbs;
    if (in_sizes[0] == 16777216) { z = d_in[0]; cbs = d_in[1]; }
    else                         { z = d_in[1]; cbs = d_in[0]; }

    float*  out      = (float*)d_out;
    float*  w2f      = (float*)d_ws;
    double* partials = (double*)((char*)d_ws + WS_PART_OFF);
    int*    flags    = (int*)((char*)d_ws + WS_FLAG_OFF);

    canary_kernel<<<1024, 256, 0, stream>>>(out);
    detect_kernel<<<1, 256, 0, stream>>>((const u16*)z, (const u16*)cbs, flags);
    w2_kernel<<<16, 256, 0, stream>>>(cbs, w2f, flags);
    rq_kernel<<<N_TOK / TM, 256, 0, stream>>>(z, cbs, w2f, out, partials, flags);
    loss_final<<<1, 256, 0, stream>>>(partials, out);
}